// Round 8
// baseline (45.275 us; speedup 1.0000x reference)
//
#include <hip/hip_runtime.h>
#include <cmath>

// RMSDLoss (batched Kabsch RMSD, mean over batch) — wave-per-row pipeline.
// R6 forensics: one-shot blocks have ~50% load-issue duty cycle (no bytes in
// flight during reduce/solve epilogues) -> ~21us vs ~9us L3-aware floor.
// R7: one WAVE per row (no barriers/LDS in hot path), 4 rows/block, grid 512.
// Per wave: 4 iterations of double-buffered 12x dwordx4 bursts (prefetch i+1
// issued before consuming i; sched_barrier(0) pins issue order -> R6 lesson).
// Mean fused via last-block counter (device-scope atomics + threadfence, G16).
// fp32 solve (absmax 0.0 across R2-R6).

constexpr int BLOCK = 256;
constexpr int NWAVE = BLOCK / 64;
constexpr int NS = 17;

template<int N>
__global__ __launch_bounds__(BLOCK) void rmsd_kernel(
    const float* __restrict__ yp,   // [B,N,3] coords (y_prime)
    const float* __restrict__ yr,   // [B,N,3] reference (y)
    float* __restrict__ rms,        // [B] scratch (d_ws+256)
    int*   __restrict__ counter,    // d_ws[0], zeroed per call
    float* __restrict__ out,        // [1] result
    int B, float invB, int nblocks)
{
    const int tid  = threadIdx.x;
    const int wave = tid >> 6, lane = tid & 63;
    const int row  = blockIdx.x * NWAVE + wave;

    float s1x=0.f,s1y=0.f,s1z=0.f, s2x=0.f,s2y=0.f,s2z=0.f, sq1=0.f,sq2=0.f;
    float c00=0.f,c01=0.f,c02=0.f,c10=0.f,c11=0.f,c12=0.f,c20=0.f,c21=0.f,c22=0.f;

    auto accum4 = [&](const float4&a0,const float4&a1,const float4&a2,
                      const float4&b0,const float4&b1,const float4&b2){
        float px[4]={a0.x,a0.w,a1.z,a2.y};
        float py[4]={a0.y,a1.x,a1.w,a2.z};
        float pz[4]={a0.z,a1.y,a2.x,a2.w};
        float qx[4]={b0.x,b0.w,b1.z,b2.y};
        float qy[4]={b0.y,b1.x,b1.w,b2.z};
        float qz[4]={b0.z,b1.y,b2.x,b2.w};
        #pragma unroll
        for (int k=0;k<4;k++){
            s1x+=px[k]; s1y+=py[k]; s1z+=pz[k];
            s2x+=qx[k]; s2y+=qy[k]; s2z+=qz[k];
            sq1 = fmaf(px[k],px[k], fmaf(py[k],py[k], fmaf(pz[k],pz[k], sq1)));
            sq2 = fmaf(qx[k],qx[k], fmaf(qy[k],qy[k], fmaf(qz[k],qz[k], sq2)));
            c00=fmaf(px[k],qx[k],c00); c01=fmaf(px[k],qy[k],c01); c02=fmaf(px[k],qz[k],c02);
            c10=fmaf(py[k],qx[k],c10); c11=fmaf(py[k],qy[k],c11); c12=fmaf(py[k],qz[k],c12);
            c20=fmaf(pz[k],qx[k],c20); c21=fmaf(pz[k],qy[k],c21); c22=fmaf(pz[k],qz[k],c22);
        }
    };

    if (row < B) {
        // Per-lane chunk = 6 consecutive float4 = 24 floats = 8 atoms (atom-
        // aligned). One iteration covers 64 lanes x 8 atoms = 512 atoms.
        const float4* p4 = (const float4*)(yp + (size_t)row * N * 3) + lane * 6;
        const float4* q4 = (const float4*)(yr + (size_t)row * N * 3) + lane * 6;
        constexpr int STRIDE = 64 * 6;            // float4 per tensor per iter
        constexpr int ITERS  = (N * 3 / 4) / STRIDE;   // 4 for N=2048

        float4 PA[6], QA[6], PB[6], QB[6];
        #pragma unroll
        for (int k=0;k<6;k++) PA[k] = p4[k];
        #pragma unroll
        for (int k=0;k<6;k++) QA[k] = q4[k];

        #pragma unroll
        for (int i = 0; i < ITERS; ++i) {
            float4* Pc = (i & 1) ? PB : PA;  float4* Qc = (i & 1) ? QB : QA;
            float4* Pn = (i & 1) ? PA : PB;  float4* Qn = (i & 1) ? QA : QB;
            if (i + 1 < ITERS) {
                const float4* pn = p4 + (size_t)(i+1) * STRIDE;
                const float4* qn = q4 + (size_t)(i+1) * STRIDE;
                #pragma unroll
                for (int k=0;k<6;k++) Pn[k] = pn[k];
                #pragma unroll
                for (int k=0;k<6;k++) Qn[k] = qn[k];
            }
            __builtin_amdgcn_sched_barrier(0);   // prefetch issues before consume
            accum4(Pc[0],Pc[1],Pc[2], Qc[0],Qc[1],Qc[2]);
            accum4(Pc[3],Pc[4],Pc[5], Qc[3],Qc[4],Qc[5]);
        }
    }

    // Wave-local reduction: 17 sums x 6 shuffle rounds. No LDS, no barriers.
    float vals[NS] = {s1x,s1y,s1z,s2x,s2y,s2z,sq1,sq2,
                      c00,c01,c02,c10,c11,c12,c20,c21,c22};
    #pragma unroll
    for (int i = 0; i < NS; ++i) {
        float v = vals[i];
        #pragma unroll
        for (int off = 32; off > 0; off >>= 1) v += __shfl_down(v, off, 64);
        vals[i] = v;
    }

    if (lane == 0 && row < B) {
        const float fn = (float)N;
        const float* t = vals;
        const float m1x=t[0]/fn, m1y=t[1]/fn, m1z=t[2]/fn;
        const float m2x=t[3]/fn, m2y=t[4]/fn, m2z=t[5]/fn;
        const float E0 = (t[6] - fn*(m1x*m1x+m1y*m1y+m1z*m1z))
                       + (t[7] - fn*(m2x*m2x+m2y*m2y+m2z*m2z));
        const float A00=t[8] -fn*m1x*m2x, A01=t[9] -fn*m1x*m2y, A02=t[10]-fn*m1x*m2z;
        const float A10=t[11]-fn*m1y*m2x, A11=t[12]-fn*m1y*m2y, A12=t[13]-fn*m1y*m2z;
        const float A20=t[14]-fn*m1z*m2x, A21=t[15]-fn*m1z*m2y, A22=t[16]-fn*m1z*m2z;

        const float det = A00*(A11*A22-A12*A21)
                        - A01*(A10*A22-A12*A20)
                        + A02*(A10*A21-A11*A20);

        const float G00 = A00*A00+A10*A10+A20*A20;
        const float G01 = A00*A01+A10*A11+A20*A21;
        const float G02 = A00*A02+A10*A12+A20*A22;
        const float G11 = A01*A01+A11*A11+A21*A21;
        const float G12 = A01*A02+A11*A12+A21*A22;
        const float G22 = A02*A02+A12*A12+A22*A22;

        const float q  = (G00+G11+G22)*(1.f/3.f);
        const float p1 = G01*G01 + G02*G02 + G12*G12;
        const float p2 = (G00-q)*(G00-q)+(G11-q)*(G11-q)+(G22-q)*(G22-q) + 2.f*p1;
        const float p  = sqrtf(p2*(1.f/6.f));
        float e1, e2, e3;
        if (p < 1e-20f) {
            e1 = e2 = e3 = q;
        } else {
            const float ip = 1.f/p;
            const float C00=(G00-q)*ip, C01=G01*ip, C02=G02*ip;
            const float C11=(G11-q)*ip, C12=G12*ip, C22=(G22-q)*ip;
            float detC = C00*(C11*C22-C12*C12)
                       - C01*(C01*C22-C12*C02)
                       + C02*(C01*C12-C11*C02);
            float rr = fminf(1.f, fmaxf(-1.f, 0.5f*detC));
            const float phi = acosf(rr)*(1.f/3.f);
            e1 = q + 2.f*p*cosf(phi);
            e3 = q + 2.f*p*cosf(phi + 2.0943951023931953f);  // +2*pi/3
            e2 = 3.f*q - e1 - e3;
        }
        const float sv0 = sqrtf(fmaxf(e1,0.f));
        const float sv1 = sqrtf(fmaxf(e2,0.f));
        const float sv2 = sqrtf(fmaxf(e3,0.f));
        const float trs = sv0 + sv1 + ((det >= 0.f) ? sv2 : -sv2);
        const float msd = fmaxf(0.f, (E0 - 2.f*trs)/fn);
        __hip_atomic_store(&rms[row], sqrtf(msd),
                           __ATOMIC_RELAXED, __HIP_MEMORY_SCOPE_AGENT);
    }

    // ---- fused mean: last block to arrive reduces rms[] ----
    __shared__ int lastflag;
    __syncthreads();                    // all waves' stores drained (vmcnt 0)
    if (tid == 0) {
        __threadfence();                // release: rms stores visible device-wide
        int old = atomicAdd(counter, 1);
        lastflag = (old == nblocks - 1);
    }
    __syncthreads();
    if (lastflag) {
        __threadfence();                // acquire: invalidate stale cached lines
        float acc = 0.f;
        for (int i = tid; i < B; i += BLOCK)
            acc += __hip_atomic_load(&rms[i],
                                     __ATOMIC_RELAXED, __HIP_MEMORY_SCOPE_AGENT);
        #pragma unroll
        for (int off = 32; off > 0; off >>= 1) acc += __shfl_down(acc, off, 64);
        __shared__ float sred[NWAVE];
        if (lane == 0) sred[wave] = acc;
        __syncthreads();
        if (tid == 0) {
            float tot = 0.f;
            #pragma unroll
            for (int w = 0; w < NWAVE; ++w) tot += sred[w];
            out[0] = tot * invB;
        }
    }
}

extern "C" void kernel_launch(void* const* d_in, const int* in_sizes, int n_in,
                              void* d_out, int out_size, void* d_ws, size_t ws_size,
                              hipStream_t stream) {
    const float* yp = (const float*)d_in[0];   // y_prime [B,N,3] f32
    const float* yr = (const float*)d_in[1];   // y       [B,N,3] f32
    const int N = 2048;
    const int B = in_sizes[0] / (N * 3);
    const int nblocks = (B + NWAVE - 1) / NWAVE;   // 512 for B=2048

    int*   counter = (int*)d_ws;
    float* rms     = (float*)((char*)d_ws + 256);

    hipMemsetAsync(d_ws, 0, 256, stream);          // zero the arrival counter
    rmsd_kernel<2048><<<nblocks, BLOCK, 0, stream>>>(
        yp, yr, rms, counter, (float*)d_out, B, 1.0f/(float)B, nblocks);
}

// Round 9
// 26.604 us; speedup vs baseline: 1.7018x; 1.7018x over previous
//
#include <hip/hip_runtime.h>
#include <cmath>

// RMSDLoss (batched Kabsch RMSD, mean over batch).
// R6 (26.6us, best): block-per-row one-shot 12-load burst, VGPR~84 -> only 6
// of 8 blocks/CU resident -> straggler round. R7 wave-per-row: regalloc broke
// the double buffer (VGPR 84 < 96 needed), grid 512 too small -> 45us.
// R8: R6 structure, but burst split into 2x6 loads so peak live data regs ~24;
// __launch_bounds__(256,8) caps VGPR at 64 -> all 8 blocks/CU co-resident,
// single round, no latency-starved tail. Per-CU MLP: 32 waves x 6KB >> 16KB
// needed for 6.8 TB/s. fp32 solve (absmax 0.0 across R2-R7), separate mean
// kernel (same-address atomic storm avoided).

constexpr int BLOCK = 256;
constexpr int NWAVE = BLOCK / 64;
constexpr int NS = 17;

template<int N>
__global__ __launch_bounds__(BLOCK, 8) void rmsd_kernel(
    const float* __restrict__ yp,   // [B,N,3] coords (y_prime)
    const float* __restrict__ yr,   // [B,N,3] reference (y)
    float* __restrict__ rms_out)    // [B]
{
    static_assert(N == BLOCK * 8, "one thread = 8 atoms = 6 float4");
    const int b   = blockIdx.x;
    const int tid = threadIdx.x;
    const size_t row = (size_t)b * (size_t)N * 3u;
    const float4* p4 = (const float4*)(yp + row) + tid * 6;
    const float4* q4 = (const float4*)(yr + row) + tid * 6;

    float s1x=0.f,s1y=0.f,s1z=0.f, s2x=0.f,s2y=0.f,s2z=0.f, sq1=0.f,sq2=0.f;
    float c00=0.f,c01=0.f,c02=0.f,c10=0.f,c11=0.f,c12=0.f,c20=0.f,c21=0.f,c22=0.f;

    auto accum4 = [&](const float4&a0,const float4&a1,const float4&a2,
                      const float4&b0,const float4&b1,const float4&b2){
        float px[4]={a0.x,a0.w,a1.z,a2.y};
        float py[4]={a0.y,a1.x,a1.w,a2.z};
        float pz[4]={a0.z,a1.y,a2.x,a2.w};
        float qx[4]={b0.x,b0.w,b1.z,b2.y};
        float qy[4]={b0.y,b1.x,b1.w,b2.z};
        float qz[4]={b0.z,b1.y,b2.x,b2.w};
        #pragma unroll
        for (int k=0;k<4;k++){
            s1x+=px[k]; s1y+=py[k]; s1z+=pz[k];
            s2x+=qx[k]; s2y+=qy[k]; s2z+=qz[k];
            sq1 = fmaf(px[k],px[k], fmaf(py[k],py[k], fmaf(pz[k],pz[k], sq1)));
            sq2 = fmaf(qx[k],qx[k], fmaf(qy[k],qy[k], fmaf(qz[k],qz[k], sq2)));
            c00=fmaf(px[k],qx[k],c00); c01=fmaf(px[k],qy[k],c01); c02=fmaf(px[k],qz[k],c02);
            c10=fmaf(py[k],qx[k],c10); c11=fmaf(py[k],qy[k],c11); c12=fmaf(py[k],qz[k],c12);
            c20=fmaf(pz[k],qx[k],c20); c21=fmaf(pz[k],qy[k],c21); c22=fmaf(pz[k],qz[k],c22);
        }
    };

    // Phase A: 6-load burst (atoms 0..3), issue all before consuming.
    {
        const float4 P0=p4[0], P1=p4[1], P2=p4[2];
        const float4 Q0=q4[0], Q1=q4[1], Q2=q4[2];
        __builtin_amdgcn_sched_barrier(0);
        accum4(P0,P1,P2, Q0,Q1,Q2);
    }
    // Phase B: 6-load burst (atoms 4..7).
    {
        const float4 P3=p4[3], P4=p4[4], P5=p4[5];
        const float4 Q3=q4[3], Q4=q4[4], Q5=q4[5];
        __builtin_amdgcn_sched_barrier(0);
        accum4(P3,P4,P5, Q3,Q4,Q5);
    }

    // Block reduction of the 17 sums.
    float vals[NS] = {s1x,s1y,s1z,s2x,s2y,s2z,sq1,sq2,
                      c00,c01,c02,c10,c11,c12,c20,c21,c22};
    __shared__ float sred[NWAVE][NS];
    const int wave = tid >> 6, lane = tid & 63;
    #pragma unroll
    for (int i = 0; i < NS; ++i) {
        float v = vals[i];
        #pragma unroll
        for (int off = 32; off > 0; off >>= 1) v += __shfl_down(v, off, 64);
        if (lane == 0) sred[wave][i] = v;
    }
    __syncthreads();

    if (tid == 0) {
        float t[NS];
        #pragma unroll
        for (int i = 0; i < NS; ++i) {
            float s = 0.f;
            #pragma unroll
            for (int w = 0; w < NWAVE; ++w) s += sred[w][i];
            t[i] = s;
        }
        const float fn = (float)N;
        const float m1x=t[0]/fn, m1y=t[1]/fn, m1z=t[2]/fn;
        const float m2x=t[3]/fn, m2y=t[4]/fn, m2z=t[5]/fn;
        const float E0 = (t[6] - fn*(m1x*m1x+m1y*m1y+m1z*m1z))
                       + (t[7] - fn*(m2x*m2x+m2y*m2y+m2z*m2z));
        const float A00=t[8] -fn*m1x*m2x, A01=t[9] -fn*m1x*m2y, A02=t[10]-fn*m1x*m2z;
        const float A10=t[11]-fn*m1y*m2x, A11=t[12]-fn*m1y*m2y, A12=t[13]-fn*m1y*m2z;
        const float A20=t[14]-fn*m1z*m2x, A21=t[15]-fn*m1z*m2y, A22=t[16]-fn*m1z*m2z;

        const float det = A00*(A11*A22-A12*A21)
                        - A01*(A10*A22-A12*A20)
                        + A02*(A10*A21-A11*A20);

        // G = A^T A (symmetric PSD); analytic eigenvalues (fp32)
        const float G00 = A00*A00+A10*A10+A20*A20;
        const float G01 = A00*A01+A10*A11+A20*A21;
        const float G02 = A00*A02+A10*A12+A20*A22;
        const float G11 = A01*A01+A11*A11+A21*A21;
        const float G12 = A01*A02+A11*A12+A21*A22;
        const float G22 = A02*A02+A12*A12+A22*A22;

        const float q  = (G00+G11+G22)*(1.f/3.f);
        const float p1 = G01*G01 + G02*G02 + G12*G12;
        const float p2 = (G00-q)*(G00-q)+(G11-q)*(G11-q)+(G22-q)*(G22-q) + 2.f*p1;
        const float p  = sqrtf(p2*(1.f/6.f));
        float e1, e2, e3;
        if (p < 1e-20f) {
            e1 = e2 = e3 = q;
        } else {
            const float ip = 1.f/p;
            const float C00=(G00-q)*ip, C01=G01*ip, C02=G02*ip;
            const float C11=(G11-q)*ip, C12=G12*ip, C22=(G22-q)*ip;
            float detC = C00*(C11*C22-C12*C12)
                       - C01*(C01*C22-C12*C02)
                       + C02*(C01*C12-C11*C02);
            float rr = fminf(1.f, fmaxf(-1.f, 0.5f*detC));
            const float phi = acosf(rr)*(1.f/3.f);
            e1 = q + 2.f*p*cosf(phi);
            e3 = q + 2.f*p*cosf(phi + 2.0943951023931953f);  // +2*pi/3
            e2 = 3.f*q - e1 - e3;
        }
        const float sv0 = sqrtf(fmaxf(e1,0.f));
        const float sv1 = sqrtf(fmaxf(e2,0.f));
        const float sv2 = sqrtf(fmaxf(e3,0.f));
        const float trs = sv0 + sv1 + ((det >= 0.f) ? sv2 : -sv2);
        const float msd = fmaxf(0.f, (E0 - 2.f*trs)/fn);
        rms_out[b] = sqrtf(msd);
    }
}

__global__ __launch_bounds__(BLOCK) void mean_kernel(
    const float* __restrict__ rms, float* __restrict__ out, int B)
{
    const int tid = threadIdx.x;
    const float4* r4 = (const float4*)rms;
    float s = 0.f;
    for (int i = tid; i < B/4; i += BLOCK) {
        float4 v = r4[i];
        s += (v.x + v.y) + (v.z + v.w);
    }
    #pragma unroll
    for (int off = 32; off > 0; off >>= 1) s += __shfl_down(s, off, 64);
    __shared__ float sred[NWAVE];
    const int wave = tid >> 6, lane = tid & 63;
    if (lane == 0) sred[wave] = s;
    __syncthreads();
    if (tid == 0) {
        float tot = 0.f;
        #pragma unroll
        for (int w = 0; w < NWAVE; ++w) tot += sred[w];
        out[0] = tot / (float)B;
    }
}

extern "C" void kernel_launch(void* const* d_in, const int* in_sizes, int n_in,
                              void* d_out, int out_size, void* d_ws, size_t ws_size,
                              hipStream_t stream) {
    const float* yp = (const float*)d_in[0];   // y_prime [B,N,3] f32
    const float* yr = (const float*)d_in[1];   // y       [B,N,3] f32
    const int N = 2048;
    const int B = in_sizes[0] / (N * 3);
    float* rms_ws = (float*)d_ws;              // B floats

    rmsd_kernel<2048><<<B, BLOCK, 0, stream>>>(yp, yr, rms_ws);
    mean_kernel<<<1, BLOCK, 0, stream>>>(rms_ws, (float*)d_out, B);
}